// Round 1
// 84.362 us; speedup vs baseline: 1.0342x; 1.0342x over previous
//
#include <hip/hip_runtime.h>

// SelfAttention: out = softmax(QK^T*s + fw)V + softmax(QK^T*s + bw)V
// B=8, L=2048, D=64, fp32 in/out. bf16 MFMA, no online max (scores bounded;
// -1e9 mask == hard zero in fp32 exp).
//
// v4: - 32 q-rows per wave (two 16-col q-tiles per MFMA pass), grid 512.
//       Halves per-wave K/V streaming per unit work: L2 traffic 512MB -> 256MB.
//       (theory: attn_v3 was L2-BW bound at ~4.3 TB/s/XCD, not pipe bound)
//     - explicit ping-pong buffers (kaA/kaB) instead of rotate -> kills the
//       32 v_mov frag copies per block.
//     - launch_bounds(256,2): ~2 WG/CU (LDS 72KB, VGPR ~200), 8 waves/CU.
//     - prepack + fragment order + in-register bperm P-transform unchanged
//       from v3 (validated, absmax 1.6e-2).
//
// MFMA 16x16x32 bf16 layouts (validated):
//   A: elem j of lane l = A[l&15][(l>>4)*8+j]
//   B: elem j of lane l = B[(l>>4)*8+j][l&15]
//   C/D: elem r of lane l = D[(l>>4)*4+r][l&15]
// bperm transform: lane(col,quad) needs P(keys quad*8..+7, q=col); sources are
// C-layout lanes 32*(quad&1)+col (lo regs) and +16 (hi regs), st0-set for
// quad<2, st1-set for quad>=2.

typedef __attribute__((ext_vector_type(8))) short short8;
typedef __attribute__((ext_vector_type(4))) float f32x4;

union Frag {
    short8 s;
    unsigned u[4];
    uint4 u4;
};

#define MFMA16(A, B, C) __builtin_amdgcn_mfma_f32_16x16x32_bf16((A), (B), (C), 0, 0, 0)

static constexpr int BB = 8, LL = 2048, DD = 64;
static constexpr float QSCALE = 0.125f * 1.44269504088896340736f;  // /sqrt(64)*log2(e)

__device__ __forceinline__ unsigned pk2(float a, float b) {
    unsigned ua = __builtin_bit_cast(unsigned, a) + 0x8000u;
    unsigned ub = __builtin_bit_cast(unsigned, b) + 0x8000u;
    return __builtin_amdgcn_perm(ub, ua, 0x07060302u);
}

__device__ __forceinline__ unsigned bperm(int addr, unsigned v) {
    return (unsigned)__builtin_amdgcn_ds_bpermute(addr, (int)v);
}

// ---------------------------------------------------------------- prepack ---
// grid 1024: [0,512) K-frags, [512,1024) V-frags.
// Kf/Vf layout: [b][jblk 0..63][frag 0..3][lane 0..63] x 4 u32 (16B).
//   K frag g=(f<<1)|h: lane(col,quad) = bf16{ K[j0+16f+col][h*32+quad*8+k] }
//   V frag g=c:        lane(col,quad) = bf16{ V[j0+quad*8+k][16c+col] }
__global__ __launch_bounds__(256)
void prepack_frags(const float* __restrict__ K, const float* __restrict__ V,
                   unsigned* __restrict__ Kf, unsigned* __restrict__ Vf) {
    const int t    = threadIdx.x;
    const int lane = t & 63;
    const int col  = lane & 15;
    const int quad = lane >> 4;
    const int g    = t >> 6;
    if (blockIdx.x < 512) {
        const int b = blockIdx.x >> 6, jblk = blockIdx.x & 63, j0 = jblk << 5;
        const int f = g >> 1, h = g & 1;
        const float* src = K + ((size_t)(b * LL) + j0 + 16 * f + col) * DD + h * 32 + quad * 8;
        float4 a0 = *(const float4*)(src);
        float4 a1 = *(const float4*)(src + 4);
        uint4 o = make_uint4(pk2(a0.x, a0.y), pk2(a0.z, a0.w),
                             pk2(a1.x, a1.y), pk2(a1.z, a1.w));
        *(uint4*)(Kf + (size_t)(b * 64 + jblk) * 1024 + t * 4) = o;
    } else {
        const int idx = blockIdx.x - 512;
        const int b = idx >> 6, jblk = idx & 63, j0 = jblk << 5;
        const float* src = V + ((size_t)(b * LL) + j0 + quad * 8) * DD + 16 * g + col;
        float e[8];
        #pragma unroll
        for (int kk = 0; kk < 8; ++kk) e[kk] = src[(size_t)kk * DD];
        uint4 o = make_uint4(pk2(e[0], e[1]), pk2(e[2], e[3]),
                             pk2(e[4], e[5]), pk2(e[6], e[7]));
        *(uint4*)(Vf + (size_t)(b * 64 + jblk) * 1024 + t * 4) = o;
    }
}

// ------------------------------------------------------------------- main ---
// grid 512: b = blk&7 (XCD slot), i0 = (blk>>3)*32. 4 waves split 2048 keys.
__global__ __launch_bounds__(256, 2)
void attn_v4(const float* __restrict__ Q, const unsigned* __restrict__ Kf,
             const unsigned* __restrict__ Vf, float* __restrict__ O) {
    // epilogue only: red [4w][2s][32q][68d] = 17408 f; lred 1024 f -> 72KB
    __shared__ __align__(16) float red[18432];

    const int tid  = threadIdx.x;
    const int w    = tid >> 6;
    const int lane = tid & 63;
    const int col  = lane & 15;
    const int quad = lane >> 4;

    const int b  = blockIdx.x & 7;
    const int i0 = (blockIdx.x >> 3) << 5;   // 32-aligned

    // ---- Q fragments (B operand), pre-scaled: qf[qt][dhalf]
    Frag qf[2][2];
    {
        const float* qr = Q + ((size_t)(b * LL) + i0 + col) * DD + quad * 8;
        #pragma unroll
        for (int qt = 0; qt < 2; ++qt) {
            const float* qp = qr + (size_t)qt * 16 * DD;
            float4 a0 = *(const float4*)(qp + 0);
            float4 a1 = *(const float4*)(qp + 4);
            float4 a2 = *(const float4*)(qp + 32);
            float4 a3 = *(const float4*)(qp + 36);
            qf[qt][0].u[0] = pk2(a0.x * QSCALE, a0.y * QSCALE);
            qf[qt][0].u[1] = pk2(a0.z * QSCALE, a0.w * QSCALE);
            qf[qt][0].u[2] = pk2(a1.x * QSCALE, a1.y * QSCALE);
            qf[qt][0].u[3] = pk2(a1.z * QSCALE, a1.w * QSCALE);
            qf[qt][1].u[0] = pk2(a2.x * QSCALE, a2.y * QSCALE);
            qf[qt][1].u[1] = pk2(a2.z * QSCALE, a2.w * QSCALE);
            qf[qt][1].u[2] = pk2(a3.x * QSCALE, a3.y * QSCALE);
            qf[qt][1].u[3] = pk2(a3.z * QSCALE, a3.w * QSCALE);
        }
    }

    const int kbase = w << 9;
    const unsigned* kp = Kf + (size_t)(b * 64 + (kbase >> 5)) * 1024 + lane * 4;
    const unsigned* vp = Vf + (size_t)(b * 64 + (kbase >> 5)) * 1024 + lane * 4;

    f32x4 zero = {0.f, 0.f, 0.f, 0.f};
    f32x4 ot[2][2][4];   // [side][qt][dfrag]
    #pragma unroll
    for (int s = 0; s < 2; ++s)
        #pragma unroll
        for (int qt = 0; qt < 2; ++qt)
            #pragma unroll
            for (int c = 0; c < 4; ++c) ot[s][qt][c] = zero;
    float lsF[2] = {0.f, 0.f}, lsB[2] = {0.f, 0.f};

    const int  bpA = (32 * (quad & 1) + col) << 2;   // bperm byte addr (lo half)
    const bool hiq = quad >= 2;                       // use key-frag-1 sources

    // preload block 0 into buffer A
    Frag kaA[4], vfA[4], kaB[4], vfB[4];
    #pragma unroll
    for (int g = 0; g < 4; ++g) {
        kaA[g].u4 = *(const uint4*)(kp + g * 256);
        vfA[g].u4 = *(const uint4*)(vp + g * 256);
    }

    auto body = [&](Frag (&ck)[4], Frag (&cv)[4], Frag (&nk)[4], Frag (&nv)[4],
                    const int blk) {
        const int j0 = kbase + (blk << 5);
        const int no = ((blk + 1) & 15) << 10;   // next-block u32 offset (wraps)
        #pragma unroll
        for (int g = 0; g < 4; ++g) {
            nk[g].u4 = *(const uint4*)(kp + no + g * 256);
            nv[g].u4 = *(const uint4*)(vp + no + g * 256);
        }

        // ---- S^T = K · (Qs)^T  (rows=keys, cols=queries), both q-tiles
        f32x4 st00 = zero, st01 = zero, st10 = zero, st11 = zero;
        st00 = MFMA16(ck[0].s, qf[0][0].s, st00);
        st00 = MFMA16(ck[1].s, qf[0][1].s, st00);
        st01 = MFMA16(ck[0].s, qf[1][0].s, st01);
        st01 = MFMA16(ck[1].s, qf[1][1].s, st01);
        st10 = MFMA16(ck[2].s, qf[0][0].s, st10);
        st10 = MFMA16(ck[3].s, qf[0][1].s, st10);
        st11 = MFMA16(ck[2].s, qf[1][0].s, st11);
        st11 = MFMA16(ck[3].s, qf[1][1].s, st11);

        float p0[2][4], p1[2][4];   // [qt][r] for key-frag 0 / 1
        #pragma unroll
        for (int r = 0; r < 4; ++r) {
            p0[0][r] = exp2f(st00[r]);
            p0[1][r] = exp2f(st01[r]);
            p1[0][r] = exp2f(st10[r]);
            p1[1][r] = exp2f(st11[r]);
        }

        const bool mixed = (j0 == i0);

        if (j0 >= i0) {   // forward side (wave-uniform)
            #pragma unroll
            for (int qt = 0; qt < 2; ++qt) {
                float m0[4], m1[4];
                if (mixed) {
                    const int ig = i0 + 16 * qt + col;
                    #pragma unroll
                    for (int r = 0; r < 4; ++r) {
                        const int jg = j0 + 4 * quad + r;
                        m0[r] = (jg >= ig) ? p0[qt][r] : 0.f;
                        m1[r] = (jg + 16 >= ig) ? p1[qt][r] : 0.f;
                    }
                } else {
                    #pragma unroll
                    for (int r = 0; r < 4; ++r) { m0[r] = p0[qt][r]; m1[r] = p1[qt][r]; }
                }
                lsF[qt] += m0[0] + m0[1] + m0[2] + m0[3] + m1[0] + m1[1] + m1[2] + m1[3];
                unsigned x01 = pk2(m0[0], m0[1]), x23 = pk2(m0[2], m0[3]);
                unsigned y01 = pk2(m1[0], m1[1]), y23 = pk2(m1[2], m1[3]);
                unsigned a0 = bperm(bpA, x01),      a1 = bperm(bpA, x23);
                unsigned a2 = bperm(bpA + 64, x01), a3 = bperm(bpA + 64, x23);
                unsigned b0 = bperm(bpA, y01),      b1 = bperm(bpA, y23);
                unsigned b2 = bperm(bpA + 64, y01), b3 = bperm(bpA + 64, y23);
                Frag pf;
                pf.u[0] = hiq ? b0 : a0;
                pf.u[1] = hiq ? b1 : a1;
                pf.u[2] = hiq ? b2 : a2;
                pf.u[3] = hiq ? b3 : a3;
                #pragma unroll
                for (int c = 0; c < 4; ++c)
                    ot[0][qt][c] = MFMA16(cv[c].s, pf.s, ot[0][qt][c]);
            }
        }
        if (j0 <= i0) {   // backward side (wave-uniform)
            #pragma unroll
            for (int qt = 0; qt < 2; ++qt) {
                float m0[4], m1[4];
                if (mixed) {
                    const int ig = i0 + 16 * qt + col;
                    #pragma unroll
                    for (int r = 0; r < 4; ++r) {
                        const int jg = j0 + 4 * quad + r;
                        m0[r] = (jg <= ig) ? p0[qt][r] : 0.f;
                        m1[r] = (jg + 16 <= ig) ? p1[qt][r] : 0.f;
                    }
                } else {
                    #pragma unroll
                    for (int r = 0; r < 4; ++r) { m0[r] = p0[qt][r]; m1[r] = p1[qt][r]; }
                }
                lsB[qt] += m0[0] + m0[1] + m0[2] + m0[3] + m1[0] + m1[1] + m1[2] + m1[3];
                unsigned x01 = pk2(m0[0], m0[1]), x23 = pk2(m0[2], m0[3]);
                unsigned y01 = pk2(m1[0], m1[1]), y23 = pk2(m1[2], m1[3]);
                unsigned a0 = bperm(bpA, x01),      a1 = bperm(bpA, x23);
                unsigned a2 = bperm(bpA + 64, x01), a3 = bperm(bpA + 64, x23);
                unsigned b0 = bperm(bpA, y01),      b1 = bperm(bpA, y23);
                unsigned b2 = bperm(bpA + 64, y01), b3 = bperm(bpA + 64, y23);
                Frag pg;
                pg.u[0] = hiq ? b0 : a0;
                pg.u[1] = hiq ? b1 : a1;
                pg.u[2] = hiq ? b2 : a2;
                pg.u[3] = hiq ? b3 : a3;
                #pragma unroll
                for (int c = 0; c < 4; ++c)
                    ot[1][qt][c] = MFMA16(cv[c].s, pg.s, ot[1][qt][c]);
            }
        }
    };

    for (int it = 0; it < 8; ++it) {
        body(kaA, vfA, kaB, vfB, 2 * it);
        body(kaB, vfB, kaA, vfA, 2 * it + 1);
    }

    // ---- cross-wave reduction
    #pragma unroll
    for (int s = 0; s < 2; ++s)
        #pragma unroll
        for (int qt = 0; qt < 2; ++qt)
            #pragma unroll
            for (int c = 0; c < 4; ++c)
                *(f32x4*)&red[((w * 2 + s) * 32 + qt * 16 + col) * 68 + 16 * c + 4 * quad] =
                    ot[s][qt][c];
    #pragma unroll
    for (int qt = 0; qt < 2; ++qt) {
        red[17408 + (((w * 2 + 0) * 2 + qt) * 4 + quad) * 16 + col] = lsF[qt];
        red[17408 + (((w * 2 + 1) * 2 + qt) * 4 + quad) * 16 + col] = lsB[qt];
    }
    __syncthreads();

    const int q  = tid >> 4;            // 0..15
    const int d0 = (tid & 15) << 2;     // 0..60
    #pragma unroll
    for (int qh = 0; qh < 2; ++qh) {
        const int qq = qh * 16 + q;     // 0..31
        float lf = 0.f, lb = 0.f;
        #pragma unroll
        for (int w2 = 0; w2 < 4; ++w2)
            #pragma unroll
            for (int qd = 0; qd < 4; ++qd) {
                lf += red[17408 + (((w2 * 2 + 0) * 2 + qh) * 4 + qd) * 16 + q];
                lb += red[17408 + (((w2 * 2 + 1) * 2 + qh) * 4 + qd) * 16 + q];
            }
        f32x4 aF = {0.f, 0.f, 0.f, 0.f}, aB = aF;
        #pragma unroll
        for (int w2 = 0; w2 < 4; ++w2) {
            aF += *(const f32x4*)&red[((w2 * 2 + 0) * 32 + qq) * 68 + d0];
            aB += *(const f32x4*)&red[((w2 * 2 + 1) * 32 + qq) * 68 + d0];
        }
        const float rf = 1.0f / lf;
        const float rb = 1.0f / lb;
        float4 o = {aF[0] * rf + aB[0] * rb, aF[1] * rf + aB[1] * rb,
                    aF[2] * rf + aB[2] * rb, aF[3] * rf + aB[3] * rb};
        *(float4*)(O + ((size_t)(b * LL) + i0 + qq) * DD + d0) = o;
    }
}

// ---------------------------------------------- v1 fallback (ws too small) --
__global__ __launch_bounds__(256)
void attn_fused_v1(const float* __restrict__ Q, const float* __restrict__ K,
                   const float* __restrict__ V, float* __restrict__ O) {
    __shared__ unsigned smem[8448];
    const int tid  = threadIdx.x;
    const int w    = tid >> 6;
    const int lane = tid & 63;
    const int col  = lane & 15;
    const int quad = lane >> 4;
    const int b  = blockIdx.x >> 7;
    const int i0 = (blockIdx.x & 127) << 4;
    const float* Qb = Q + (size_t)(b * LL + i0) * DD;
    const float* Kb = K + (size_t)b * LL * DD;
    const float* Vb = V + (size_t)b * LL * DD;
    unsigned* VT = smem + w * 1280;
    unsigned* Pb = smem + 5120 + w * 640;
    Frag qf[2];
    {
        const float* qr = Qb + col * DD + quad * 8;
        float4 a0 = *(const float4*)(qr + 0);
        float4 a1 = *(const float4*)(qr + 4);
        float4 a2 = *(const float4*)(qr + 32);
        float4 a3 = *(const float4*)(qr + 36);
        qf[0].u[0] = pk2(a0.x * QSCALE, a0.y * QSCALE);
        qf[0].u[1] = pk2(a0.z * QSCALE, a0.w * QSCALE);
        qf[0].u[2] = pk2(a1.x * QSCALE, a1.y * QSCALE);
        qf[0].u[3] = pk2(a1.z * QSCALE, a1.w * QSCALE);
        qf[1].u[0] = pk2(a2.x * QSCALE, a2.y * QSCALE);
        qf[1].u[1] = pk2(a2.z * QSCALE, a2.w * QSCALE);
        qf[1].u[2] = pk2(a3.x * QSCALE, a3.y * QSCALE);
        qf[1].u[3] = pk2(a3.z * QSCALE, a3.w * QSCALE);
    }
    Frag ones;
    ones.u[0] = ones.u[1] = ones.u[2] = ones.u[3] = 0x3F803F80u;
    f32x4 zero = {0.f, 0.f, 0.f, 0.f};
    f32x4 ot[2][4];
    f32x4 lacc[2];
    lacc[0] = zero; lacc[1] = zero;
    for (int s = 0; s < 2; ++s)
        for (int c = 0; c < 4; ++c) ot[s][c] = zero;
    const int kbase = w << 9;
    const int dj0   = i0 & ~31;
    for (int blk = 0; blk < 16; ++blk) {
        const int j0 = kbase + (blk << 5);
        Frag ka[2][2];
        for (int f = 0; f < 2; ++f) {
            const float* kr = Kb + (size_t)(j0 + f * 16 + col) * DD + quad * 8;
            float4 c0 = *(const float4*)(kr + 0);
            float4 c1 = *(const float4*)(kr + 4);
            float4 c2 = *(const float4*)(kr + 32);
            float4 c3 = *(const float4*)(kr + 36);
            ka[f][0].u[0] = pk2(c0.x, c0.y);
            ka[f][0].u[1] = pk2(c0.z, c0.w);
            ka[f][0].u[2] = pk2(c1.x, c1.y);
            ka[f][0].u[3] = pk2(c1.z, c1.w);
            ka[f][1].u[0] = pk2(c2.x, c2.y);
            ka[f][1].u[1] = pk2(c2.z, c2.w);
            ka[f][1].u[2] = pk2(c3.x, c3.y);
            ka[f][1].u[3] = pk2(c3.z, c3.w);
        }
        for (int u = 0; u < 4; ++u) {
            const int d0 = u * 16 + quad * 4;
            const float* va = Vb + (size_t)(j0 + 2 * col) * DD + d0;
            float4 x = *(const float4*)(va);
            float4 y = *(const float4*)(va + DD);
            VT[(d0 + 0) * 20 + col] = pk2(x.x, y.x);
            VT[(d0 + 1) * 20 + col] = pk2(x.y, y.y);
            VT[(d0 + 2) * 20 + col] = pk2(x.z, y.z);
            VT[(d0 + 3) * 20 + col] = pk2(x.w, y.w);
        }
        f32x4 st0 = zero, st1 = zero;
        st0 = MFMA16(ka[0][0].s, qf[0].s, st0);
        st0 = MFMA16(ka[0][1].s, qf[1].s, st0);
        st1 = MFMA16(ka[1][0].s, qf[0].s, st1);
        st1 = MFMA16(ka[1][1].s, qf[1].s, st1);
        float p0[4], p1[4];
        for (int r = 0; r < 4; ++r) { p0[r] = exp2f(st0[r]); p1[r] = exp2f(st1[r]); }
        bool doF, doB;
        if (j0 == dj0) {
            const int ig = i0 + col;
            unsigned* prowF = Pb + col * 20 + quad * 2;
            unsigned* prowB = prowF + 320;
            float m0[4], m1[4];
            for (int r = 0; r < 4; ++r) {
                const int jg = j0 + 4 * quad + r;
                m0[r] = (jg >= ig) ? p0[r] : 0.f;
                m1[r] = (jg + 16 >= ig) ? p1[r] : 0.f;
            }
            prowF[0] = pk2(m0[0], m0[1]);
            prowF[1] = pk2(m0[2], m0[3]);
            prowF[8] = pk2(m1[0], m1[1]);
            prowF[9] = pk2(m1[2], m1[3]);
            for (int r = 0; r < 4; ++r) {
                const int jg = j0 + 4 * quad + r;
                m0[r] = (jg <= ig) ? p0[r] : 0.f;
                m1[r] = (jg + 16 <= ig) ? p1[r] : 0.f;
            }
            prowB[0] = pk2(m0[0], m0[1]);
            prowB[1] = pk2(m0[2], m0[3]);
            prowB[8] = pk2(m1[0], m1[1]);
            prowB[9] = pk2(m1[2], m1[3]);
            doF = true; doB = true;
        } else if (j0 < i0) {
            unsigned* prowB = Pb + 320 + col * 20 + quad * 2;
            prowB[0] = pk2(p0[0], p0[1]);
            prowB[1] = pk2(p0[2], p0[3]);
            prowB[8] = pk2(p1[0], p1[1]);
            prowB[9] = pk2(p1[2], p1[3]);
            doF = false; doB = true;
        } else {
            unsigned* prowF = Pb + col * 20 + quad * 2;
            prowF[0] = pk2(p0[0], p0[1]);
            prowF[1] = pk2(p0[2], p0[3]);
            prowF[8] = pk2(p1[0], p1[1]);
            prowF[9] = pk2(p1[2], p1[3]);
            doF = true; doB = false;
        }
        Frag vfr[4];
        for (int c = 0; c < 4; ++c)
            vfr[c].u4 = *(const uint4*)(VT + (16 * c + col) * 20 + quad * 4);
        if (doF) {
            Frag pf; pf.u4 = *(const uint4*)(Pb + col * 20 + quad * 4);
            lacc[0] = MFMA16(ones.s, pf.s, lacc[0]);
            for (int c = 0; c < 4; ++c) ot[0][c] = MFMA16(vfr[c].s, pf.s, ot[0][c]);
        }
        if (doB) {
            Frag pg; pg.u4 = *(const uint4*)(Pb + 320 + col * 20 + quad * 4);
            lacc[1] = MFMA16(ones.s, pg.s, lacc[1]);
            for (int c = 0; c < 4; ++c) ot[1][c] = MFMA16(vfr[c].s, pg.s, ot[1][c]);
        }
    }
    __syncthreads();
    float* red  = (float*)smem;
    float* lred = (float*)(smem + 8192);
    for (int s = 0; s < 2; ++s)
        for (int c = 0; c < 4; ++c)
            for (int r = 0; r < 4; ++r)
                red[((w * 2 + s) * 64 + 16 * c + 4 * quad + r) * 16 + col] = ot[s][c][r];
    if (lane < 16) {
        lred[(w * 2 + 0) * 16 + col] = lacc[0][0];
        lred[(w * 2 + 1) * 16 + col] = lacc[1][0];
    }
    __syncthreads();
    const int ri = tid >> 4;
    const int db = (tid & 15) << 2;
    float lf = 0.f, lb = 0.f;
    for (int w2 = 0; w2 < 4; ++w2) {
        lf += lred[(w2 * 2 + 0) * 16 + ri];
        lb += lred[(w2 * 2 + 1) * 16 + ri];
    }
    const float rf = 1.0f / lf;
    const float rb = 1.0f / lb;
    float acc[4];
    for (int kk = 0; kk < 4; ++kk) {
        float af = 0.f, ab = 0.f;
        for (int w2 = 0; w2 < 4; ++w2) {
            af += red[((w2 * 2 + 0) * 64 + db + kk) * 16 + ri];
            ab += red[((w2 * 2 + 1) * 64 + db + kk) * 16 + ri];
        }
        acc[kk] = af * rf + ab * rb;
    }
    float4 o = {acc[0], acc[1], acc[2], acc[3]};
    *(float4*)(O + (size_t)(b * LL + i0 + ri) * DD + db) = o;
}

extern "C" void kernel_launch(void* const* d_in, const int* in_sizes, int n_in,
                              void* d_out, int out_size, void* d_ws, size_t ws_size,
                              hipStream_t stream) {
    const float* q = (const float*)d_in[0];
    const float* k = (const float*)d_in[1];
    const float* v = (const float*)d_in[2];
    float* o = (float*)d_out;
    (void)in_sizes; (void)n_in; (void)out_size;

    // Kf + Vf: each [8][64] blocks x 4KB = 2MB -> 4MB total
    const size_t WS_NEED = (size_t)2 * BB * 64 * 1024 * 4 * sizeof(unsigned);
    if (ws_size >= WS_NEED) {
        unsigned* Kf = (unsigned*)d_ws;
        unsigned* Vf = Kf + (size_t)BB * 64 * 1024;
        prepack_frags<<<dim3(1024), dim3(256), 0, stream>>>(k, v, Kf, Vf);
        attn_v4<<<dim3(512), dim3(256), 0, stream>>>(q, Kf, Vf, o);
    } else {
        attn_fused_v1<<<dim3(BB * (LL / 16)), dim3(256), 0, stream>>>(q, k, v, o);
    }
}

// Round 2
// 83.182 us; speedup vs baseline: 1.0488x; 1.0142x over previous
//
#include <hip/hip_runtime.h>

// SelfAttention: out = softmax(QK^T*s + fw)V + softmax(QK^T*s + bw)V
// B=8, L=2048, D=64, fp32 in/out. bf16 MFMA, no online max (scores bounded;
// -1e9 mask == hard zero in fp32 exp).
//
// v5: - prepack rewritten: one WG per (b,jblk); coalesced float4 loads of the
//       contiguous 32x64 K/V block, bf16-pair convert into LDS [32][36]u32
//       (pad->conflict-light), 1 barrier, fragment gather via ds_read_b128
//       (K) / ds_read_b32+v_perm (V), coalesced uint4 stores. No strided
//       global access left (v4's V-path did 8 scalar loads @ stride 256B).
//     - attn: K ping-pong kept (consumed at block top), V single-buffered
//       (loaded at block top, consumed post-softmax ~200+cyc later -> L2
//       latency covered without double buffer; -16 VGPR).
//     - s_setprio(1) around MFMA clusters (T5: +4-7% on barrier-free
//       multi-wave attn structures).
//     - grid 512, 32 q-rows/WG, launch_bounds(256,2), epilogue unchanged.
//
// MFMA 16x16x32 bf16 layouts (validated):
//   A: elem j of lane l = A[l&15][(l>>4)*8+j]
//   B: elem j of lane l = B[(l>>4)*8+j][l&15]
//   C/D: elem r of lane l = D[(l>>4)*4+r][l&15]
// bperm transform: lane(col,quad) needs P(keys quad*8..+7, q=col); sources are
// C-layout lanes 32*(quad&1)+col (lo regs) and +16 (hi regs), st0-set for
// quad<2, st1-set for quad>=2.

typedef __attribute__((ext_vector_type(8))) short short8;
typedef __attribute__((ext_vector_type(4))) float f32x4;

union Frag {
    short8 s;
    unsigned u[4];
    uint4 u4;
};

#define MFMA16(A, B, C) __builtin_amdgcn_mfma_f32_16x16x32_bf16((A), (B), (C), 0, 0, 0)

static constexpr int BB = 8, LL = 2048, DD = 64;
static constexpr float QSCALE = 0.125f * 1.44269504088896340736f;  // /sqrt(64)*log2(e)

__device__ __forceinline__ unsigned pk2(float a, float b) {
    unsigned ua = __builtin_bit_cast(unsigned, a) + 0x8000u;
    unsigned ub = __builtin_bit_cast(unsigned, b) + 0x8000u;
    return __builtin_amdgcn_perm(ub, ua, 0x07060302u);
}

__device__ __forceinline__ unsigned bperm(int addr, unsigned v) {
    return (unsigned)__builtin_amdgcn_ds_bpermute(addr, (int)v);
}

// ---------------------------------------------------------------- prepack ---
// grid 512: one WG per (b, jblk). Kf/Vf layout (unchanged from v3/v4):
//   [b][jblk 0..63][frag 0..3][lane 0..63] x 4 u32 (16B).
//   K frag g=(f<<1)|h: lane(col,quad) = bf16{ K[j0+16f+col][h*32+quad*8+k] }
//   V frag g=c:        lane(col,quad) = bf16{ V[j0+quad*8+k][16c+col] }
__global__ __launch_bounds__(256)
void prepack_v2(const float* __restrict__ K, const float* __restrict__ V,
                unsigned* __restrict__ Kf, unsigned* __restrict__ Vf) {
    // [32 rows][36 u32] bf16-pairs; pad 36 keeps bank aliasing <= ~2-way.
    __shared__ unsigned lk[32 * 36];
    __shared__ unsigned lv[32 * 36];

    const int t  = threadIdx.x;
    const int bx = blockIdx.x;           // b*64 + jblk
    const int b = bx >> 6, jblk = bx & 63;
    const size_t base = ((size_t)(b * LL) + (jblk << 5)) * DD;  // floats

    const float4* K4 = (const float4*)(K + base);
    const float4* V4 = (const float4*)(V + base);
    #pragma unroll
    for (int rep = 0; rep < 2; ++rep) {
        const int m   = t + rep * 256;       // float4 index 0..511 in 32x64 block
        const float4 x = K4[m];
        const float4 y = V4[m];
        const int row = m >> 4;
        const int cu  = (m & 15) * 2;        // u32 col (bf16 pair)
        unsigned* dk = &lk[row * 36 + cu];
        dk[0] = pk2(x.x, x.y);
        dk[1] = pk2(x.z, x.w);
        unsigned* dv = &lv[row * 36 + cu];
        dv[0] = pk2(y.x, y.y);
        dv[1] = pk2(y.z, y.w);
    }
    __syncthreads();

    const int lane = t & 63, col = lane & 15, quad = lane >> 4, g = t >> 6;

    // K fragment gather: rows 16f+col, u32 cols 16h+4q .. +3 (ds_read_b128)
    {
        const int f = g >> 1, h = g & 1;
        const uint4 o = *(const uint4*)&lk[(16 * f + col) * 36 + 16 * h + 4 * quad];
        *(uint4*)(Kf + (size_t)bx * 1024 + t * 4) = o;
    }
    // V fragment gather: rows 8q+k (k=0..7), column 16g+col.
    // LDS u32 (16g+col)>>1 holds {col even half, col odd half}; select by col&1.
    {
        unsigned r[8];
        const int cu = (16 * g + col) >> 1;
        #pragma unroll
        for (int k2 = 0; k2 < 8; ++k2) r[k2] = lv[(8 * quad + k2) * 36 + cu];
        const unsigned sel = (col & 1) ? 0x07060302u : 0x05040100u;
        const uint4 o = make_uint4(__builtin_amdgcn_perm(r[1], r[0], sel),
                                   __builtin_amdgcn_perm(r[3], r[2], sel),
                                   __builtin_amdgcn_perm(r[5], r[4], sel),
                                   __builtin_amdgcn_perm(r[7], r[6], sel));
        *(uint4*)(Vf + (size_t)bx * 1024 + t * 4) = o;
    }
}

// ------------------------------------------------------------------- main ---
// grid 512: b = blk&7 (XCD slot), i0 = (blk>>3)*32. 4 waves split 2048 keys.
__global__ __launch_bounds__(256, 2)
void attn_v5(const float* __restrict__ Q, const unsigned* __restrict__ Kf,
             const unsigned* __restrict__ Vf, float* __restrict__ O) {
    // epilogue only: red [4w][2s][32q][68d] = 17408 f; lred 1024 f -> 72KB
    __shared__ __align__(16) float red[18432];

    const int tid  = threadIdx.x;
    const int w    = tid >> 6;
    const int lane = tid & 63;
    const int col  = lane & 15;
    const int quad = lane >> 4;

    const int b  = blockIdx.x & 7;
    const int i0 = (blockIdx.x >> 3) << 5;   // 32-aligned

    // ---- Q fragments (B operand), pre-scaled: qf[qt][dhalf]
    Frag qf[2][2];
    {
        const float* qr = Q + ((size_t)(b * LL) + i0 + col) * DD + quad * 8;
        #pragma unroll
        for (int qt = 0; qt < 2; ++qt) {
            const float* qp = qr + (size_t)qt * 16 * DD;
            float4 a0 = *(const float4*)(qp + 0);
            float4 a1 = *(const float4*)(qp + 4);
            float4 a2 = *(const float4*)(qp + 32);
            float4 a3 = *(const float4*)(qp + 36);
            qf[qt][0].u[0] = pk2(a0.x * QSCALE, a0.y * QSCALE);
            qf[qt][0].u[1] = pk2(a0.z * QSCALE, a0.w * QSCALE);
            qf[qt][0].u[2] = pk2(a1.x * QSCALE, a1.y * QSCALE);
            qf[qt][0].u[3] = pk2(a1.z * QSCALE, a1.w * QSCALE);
            qf[qt][1].u[0] = pk2(a2.x * QSCALE, a2.y * QSCALE);
            qf[qt][1].u[1] = pk2(a2.z * QSCALE, a2.w * QSCALE);
            qf[qt][1].u[2] = pk2(a3.x * QSCALE, a3.y * QSCALE);
            qf[qt][1].u[3] = pk2(a3.z * QSCALE, a3.w * QSCALE);
        }
    }

    const int kbase = w << 9;
    const unsigned* kp = Kf + (size_t)(b * 64 + (kbase >> 5)) * 1024 + lane * 4;
    const unsigned* vp = Vf + (size_t)(b * 64 + (kbase >> 5)) * 1024 + lane * 4;

    f32x4 zero = {0.f, 0.f, 0.f, 0.f};
    f32x4 ot[2][2][4];   // [side][qt][dfrag]
    #pragma unroll
    for (int s = 0; s < 2; ++s)
        #pragma unroll
        for (int qt = 0; qt < 2; ++qt)
            #pragma unroll
            for (int c = 0; c < 4; ++c) ot[s][qt][c] = zero;
    float lsF[2] = {0.f, 0.f}, lsB[2] = {0.f, 0.f};

    const int  bpA = (32 * (quad & 1) + col) << 2;   // bperm byte addr (lo half)
    const bool hiq = quad >= 2;                       // use key-frag-1 sources

    // preload K block 0 into buffer A (V is single-buffered per block)
    Frag kaA[4], kaB[4];
    #pragma unroll
    for (int g = 0; g < 4; ++g) kaA[g].u4 = *(const uint4*)(kp + g * 256);

    auto body = [&](Frag (&ck)[4], Frag (&nk)[4], const int blk) {
        const int j0  = kbase + (blk << 5);
        const int cur = blk << 10;               // current-block u32 offset
        const int nxt = ((blk + 1) & 15) << 10;  // next-block u32 offset (wraps)
        // prefetch next K; load current V (consumed post-softmax -> latency ok)
        #pragma unroll
        for (int g = 0; g < 4; ++g) nk[g].u4 = *(const uint4*)(kp + nxt + g * 256);
        Frag cv[4];
        #pragma unroll
        for (int g = 0; g < 4; ++g) cv[g].u4 = *(const uint4*)(vp + cur + g * 256);

        // ---- S^T = K · (Qs)^T  (rows=keys, cols=queries), both q-tiles
        f32x4 st00 = zero, st01 = zero, st10 = zero, st11 = zero;
        __builtin_amdgcn_s_setprio(1);
        st00 = MFMA16(ck[0].s, qf[0][0].s, st00);
        st00 = MFMA16(ck[1].s, qf[0][1].s, st00);
        st01 = MFMA16(ck[0].s, qf[1][0].s, st01);
        st01 = MFMA16(ck[1].s, qf[1][1].s, st01);
        st10 = MFMA16(ck[2].s, qf[0][0].s, st10);
        st10 = MFMA16(ck[3].s, qf[0][1].s, st10);
        st11 = MFMA16(ck[2].s, qf[1][0].s, st11);
        st11 = MFMA16(ck[3].s, qf[1][1].s, st11);
        __builtin_amdgcn_s_setprio(0);

        float p0[2][4], p1[2][4];   // [qt][r] for key-frag 0 / 1
        #pragma unroll
        for (int r = 0; r < 4; ++r) {
            p0[0][r] = exp2f(st00[r]);
            p0[1][r] = exp2f(st01[r]);
            p1[0][r] = exp2f(st10[r]);
            p1[1][r] = exp2f(st11[r]);
        }

        const bool mixed = (j0 == i0);

        if (j0 >= i0) {   // forward side (wave-uniform)
            #pragma unroll
            for (int qt = 0; qt < 2; ++qt) {
                float m0[4], m1[4];
                if (mixed) {
                    const int ig = i0 + 16 * qt + col;
                    #pragma unroll
                    for (int r = 0; r < 4; ++r) {
                        const int jg = j0 + 4 * quad + r;
                        m0[r] = (jg >= ig) ? p0[qt][r] : 0.f;
                        m1[r] = (jg + 16 >= ig) ? p1[qt][r] : 0.f;
                    }
                } else {
                    #pragma unroll
                    for (int r = 0; r < 4; ++r) { m0[r] = p0[qt][r]; m1[r] = p1[qt][r]; }
                }
                lsF[qt] += m0[0] + m0[1] + m0[2] + m0[3] + m1[0] + m1[1] + m1[2] + m1[3];
                unsigned x01 = pk2(m0[0], m0[1]), x23 = pk2(m0[2], m0[3]);
                unsigned y01 = pk2(m1[0], m1[1]), y23 = pk2(m1[2], m1[3]);
                unsigned a0 = bperm(bpA, x01),      a1 = bperm(bpA, x23);
                unsigned a2 = bperm(bpA + 64, x01), a3 = bperm(bpA + 64, x23);
                unsigned b0 = bperm(bpA, y01),      b1 = bperm(bpA, y23);
                unsigned b2 = bperm(bpA + 64, y01), b3 = bperm(bpA + 64, y23);
                Frag pf;
                pf.u[0] = hiq ? b0 : a0;
                pf.u[1] = hiq ? b1 : a1;
                pf.u[2] = hiq ? b2 : a2;
                pf.u[3] = hiq ? b3 : a3;
                __builtin_amdgcn_s_setprio(1);
                #pragma unroll
                for (int c = 0; c < 4; ++c)
                    ot[0][qt][c] = MFMA16(cv[c].s, pf.s, ot[0][qt][c]);
                __builtin_amdgcn_s_setprio(0);
            }
        }
        if (j0 <= i0) {   // backward side (wave-uniform)
            #pragma unroll
            for (int qt = 0; qt < 2; ++qt) {
                float m0[4], m1[4];
                if (mixed) {
                    const int ig = i0 + 16 * qt + col;
                    #pragma unroll
                    for (int r = 0; r < 4; ++r) {
                        const int jg = j0 + 4 * quad + r;
                        m0[r] = (jg <= ig) ? p0[qt][r] : 0.f;
                        m1[r] = (jg + 16 <= ig) ? p1[qt][r] : 0.f;
                    }
                } else {
                    #pragma unroll
                    for (int r = 0; r < 4; ++r) { m0[r] = p0[qt][r]; m1[r] = p1[qt][r]; }
                }
                lsB[qt] += m0[0] + m0[1] + m0[2] + m0[3] + m1[0] + m1[1] + m1[2] + m1[3];
                unsigned x01 = pk2(m0[0], m0[1]), x23 = pk2(m0[2], m0[3]);
                unsigned y01 = pk2(m1[0], m1[1]), y23 = pk2(m1[2], m1[3]);
                unsigned a0 = bperm(bpA, x01),      a1 = bperm(bpA, x23);
                unsigned a2 = bperm(bpA + 64, x01), a3 = bperm(bpA + 64, x23);
                unsigned b0 = bperm(bpA, y01),      b1 = bperm(bpA, y23);
                unsigned b2 = bperm(bpA + 64, y01), b3 = bperm(bpA + 64, y23);
                Frag pg;
                pg.u[0] = hiq ? b0 : a0;
                pg.u[1] = hiq ? b1 : a1;
                pg.u[2] = hiq ? b2 : a2;
                pg.u[3] = hiq ? b3 : a3;
                __builtin_amdgcn_s_setprio(1);
                #pragma unroll
                for (int c = 0; c < 4; ++c)
                    ot[1][qt][c] = MFMA16(cv[c].s, pg.s, ot[1][qt][c]);
                __builtin_amdgcn_s_setprio(0);
            }
        }
    };

    for (int it = 0; it < 8; ++it) {
        body(kaA, kaB, 2 * it);
        body(kaB, kaA, 2 * it + 1);
    }

    // ---- cross-wave reduction
    #pragma unroll
    for (int s = 0; s < 2; ++s)
        #pragma unroll
        for (int qt = 0; qt < 2; ++qt)
            #pragma unroll
            for (int c = 0; c < 4; ++c)
                *(f32x4*)&red[((w * 2 + s) * 32 + qt * 16 + col) * 68 + 16 * c + 4 * quad] =
                    ot[s][qt][c];
    #pragma unroll
    for (int qt = 0; qt < 2; ++qt) {
        red[17408 + (((w * 2 + 0) * 2 + qt) * 4 + quad) * 16 + col] = lsF[qt];
        red[17408 + (((w * 2 + 1) * 2 + qt) * 4 + quad) * 16 + col] = lsB[qt];
    }
    __syncthreads();

    const int q  = tid >> 4;            // 0..15
    const int d0 = (tid & 15) << 2;     // 0..60
    #pragma unroll
    for (int qh = 0; qh < 2; ++qh) {
        const int qq = qh * 16 + q;     // 0..31
        float lf = 0.f, lb = 0.f;
        #pragma unroll
        for (int w2 = 0; w2 < 4; ++w2)
            #pragma unroll
            for (int qd = 0; qd < 4; ++qd) {
                lf += red[17408 + (((w2 * 2 + 0) * 2 + qh) * 4 + qd) * 16 + q];
                lb += red[17408 + (((w2 * 2 + 1) * 2 + qh) * 4 + qd) * 16 + q];
            }
        f32x4 aF = {0.f, 0.f, 0.f, 0.f}, aB = aF;
        #pragma unroll
        for (int w2 = 0; w2 < 4; ++w2) {
            aF += *(const f32x4*)&red[((w2 * 2 + 0) * 32 + qq) * 68 + d0];
            aB += *(const f32x4*)&red[((w2 * 2 + 1) * 32 + qq) * 68 + d0];
        }
        const float rf = 1.0f / lf;
        const float rb = 1.0f / lb;
        float4 o = {aF[0] * rf + aB[0] * rb, aF[1] * rf + aB[1] * rb,
                    aF[2] * rf + aB[2] * rb, aF[3] * rf + aB[3] * rb};
        *(float4*)(O + ((size_t)(b * LL) + i0 + qq) * DD + d0) = o;
    }
}

// ---------------------------------------------- v1 fallback (ws too small) --
__global__ __launch_bounds__(256)
void attn_fused_v1(const float* __restrict__ Q, const float* __restrict__ K,
                   const float* __restrict__ V, float* __restrict__ O) {
    __shared__ unsigned smem[8448];
    const int tid  = threadIdx.x;
    const int w    = tid >> 6;
    const int lane = tid & 63;
    const int col  = lane & 15;
    const int quad = lane >> 4;
    const int b  = blockIdx.x >> 7;
    const int i0 = (blockIdx.x & 127) << 4;
    const float* Qb = Q + (size_t)(b * LL + i0) * DD;
    const float* Kb = K + (size_t)b * LL * DD;
    const float* Vb = V + (size_t)b * LL * DD;
    unsigned* VT = smem + w * 1280;
    unsigned* Pb = smem + 5120 + w * 640;
    Frag qf[2];
    {
        const float* qr = Qb + col * DD + quad * 8;
        float4 a0 = *(const float4*)(qr + 0);
        float4 a1 = *(const float4*)(qr + 4);
        float4 a2 = *(const float4*)(qr + 32);
        float4 a3 = *(const float4*)(qr + 36);
        qf[0].u[0] = pk2(a0.x * QSCALE, a0.y * QSCALE);
        qf[0].u[1] = pk2(a0.z * QSCALE, a0.w * QSCALE);
        qf[0].u[2] = pk2(a1.x * QSCALE, a1.y * QSCALE);
        qf[0].u[3] = pk2(a1.z * QSCALE, a1.w * QSCALE);
        qf[1].u[0] = pk2(a2.x * QSCALE, a2.y * QSCALE);
        qf[1].u[1] = pk2(a2.z * QSCALE, a2.w * QSCALE);
        qf[1].u[2] = pk2(a3.x * QSCALE, a3.y * QSCALE);
        qf[1].u[3] = pk2(a3.z * QSCALE, a3.w * QSCALE);
    }
    Frag ones;
    ones.u[0] = ones.u[1] = ones.u[2] = ones.u[3] = 0x3F803F80u;
    f32x4 zero = {0.f, 0.f, 0.f, 0.f};
    f32x4 ot[2][4];
    f32x4 lacc[2];
    lacc[0] = zero; lacc[1] = zero;
    for (int s = 0; s < 2; ++s)
        for (int c = 0; c < 4; ++c) ot[s][c] = zero;
    const int kbase = w << 9;
    const int dj0   = i0 & ~31;
    for (int blk = 0; blk < 16; ++blk) {
        const int j0 = kbase + (blk << 5);
        Frag ka[2][2];
        for (int f = 0; f < 2; ++f) {
            const float* kr = Kb + (size_t)(j0 + f * 16 + col) * DD + quad * 8;
            float4 c0 = *(const float4*)(kr + 0);
            float4 c1 = *(const float4*)(kr + 4);
            float4 c2 = *(const float4*)(kr + 32);
            float4 c3 = *(const float4*)(kr + 36);
            ka[f][0].u[0] = pk2(c0.x, c0.y);
            ka[f][0].u[1] = pk2(c0.z, c0.w);
            ka[f][0].u[2] = pk2(c1.x, c1.y);
            ka[f][0].u[3] = pk2(c1.z, c1.w);
            ka[f][1].u[0] = pk2(c2.x, c2.y);
            ka[f][1].u[1] = pk2(c2.z, c2.w);
            ka[f][1].u[2] = pk2(c3.x, c3.y);
            ka[f][1].u[3] = pk2(c3.z, c3.w);
        }
        for (int u = 0; u < 4; ++u) {
            const int d0 = u * 16 + quad * 4;
            const float* va = Vb + (size_t)(j0 + 2 * col) * DD + d0;
            float4 x = *(const float4*)(va);
            float4 y = *(const float4*)(va + DD);
            VT[(d0 + 0) * 20 + col] = pk2(x.x, y.x);
            VT[(d0 + 1) * 20 + col] = pk2(x.y, y.y);
            VT[(d0 + 2) * 20 + col] = pk2(x.z, y.z);
            VT[(d0 + 3) * 20 + col] = pk2(x.w, y.w);
        }
        f32x4 st0 = zero, st1 = zero;
        st0 = MFMA16(ka[0][0].s, qf[0].s, st0);
        st0 = MFMA16(ka[0][1].s, qf[1].s, st0);
        st1 = MFMA16(ka[1][0].s, qf[0].s, st1);
        st1 = MFMA16(ka[1][1].s, qf[1].s, st1);
        float p0[4], p1[4];
        for (int r = 0; r < 4; ++r) { p0[r] = exp2f(st0[r]); p1[r] = exp2f(st1[r]); }
        bool doF, doB;
        if (j0 == dj0) {
            const int ig = i0 + col;
            unsigned* prowF = Pb + col * 20 + quad * 2;
            unsigned* prowB = prowF + 320;
            float m0[4], m1[4];
            for (int r = 0; r < 4; ++r) {
                const int jg = j0 + 4 * quad + r;
                m0[r] = (jg >= ig) ? p0[r] : 0.f;
                m1[r] = (jg + 16 >= ig) ? p1[r] : 0.f;
            }
            prowF[0] = pk2(m0[0], m0[1]);
            prowF[1] = pk2(m0[2], m0[3]);
            prowF[8] = pk2(m1[0], m1[1]);
            prowF[9] = pk2(m1[2], m1[3]);
            for (int r = 0; r < 4; ++r) {
                const int jg = j0 + 4 * quad + r;
                m0[r] = (jg <= ig) ? p0[r] : 0.f;
                m1[r] = (jg + 16 <= ig) ? p1[r] : 0.f;
            }
            prowB[0] = pk2(m0[0], m0[1]);
            prowB[1] = pk2(m0[2], m0[3]);
            prowB[8] = pk2(m1[0], m1[1]);
            prowB[9] = pk2(m1[2], m1[3]);
            doF = true; doB = true;
        } else if (j0 < i0) {
            unsigned* prowB = Pb + 320 + col * 20 + quad * 2;
            prowB[0] = pk2(p0[0], p0[1]);
            prowB[1] = pk2(p0[2], p0[3]);
            prowB[8] = pk2(p1[0], p1[1]);
            prowB[9] = pk2(p1[2], p1[3]);
            doF = false; doB = true;
        } else {
            unsigned* prowF = Pb + col * 20 + quad * 2;
            prowF[0] = pk2(p0[0], p0[1]);
            prowF[1] = pk2(p0[2], p0[3]);
            prowF[8] = pk2(p1[0], p1[1]);
            prowF[9] = pk2(p1[2], p1[3]);
            doF = true; doB = false;
        }
        Frag vfr[4];
        for (int c = 0; c < 4; ++c)
            vfr[c].u4 = *(const uint4*)(VT + (16 * c + col) * 20 + quad * 4);
        if (doF) {
            Frag pf; pf.u4 = *(const uint4*)(Pb + col * 20 + quad * 4);
            lacc[0] = MFMA16(ones.s, pf.s, lacc[0]);
            for (int c = 0; c < 4; ++c) ot[0][c] = MFMA16(vfr[c].s, pf.s, ot[0][c]);
        }
        if (doB) {
            Frag pg; pg.u4 = *(const uint4*)(Pb + 320 + col * 20 + quad * 4);
            lacc[1] = MFMA16(ones.s, pg.s, lacc[1]);
            for (int c = 0; c < 4; ++c) ot[1][c] = MFMA16(vfr[c].s, pg.s, ot[1][c]);
        }
    }
    __syncthreads();
    float* red  = (float*)smem;
    float* lred = (float*)(smem + 8192);
    for (int s = 0; s < 2; ++s)
        for (int c = 0; c < 4; ++c)
            for (int r = 0; r < 4; ++r)
                red[((w * 2 + s) * 64 + 16 * c + 4 * quad + r) * 16 + col] = ot[s][c][r];
    if (lane < 16) {
        lred[(w * 2 + 0) * 16 + col] = lacc[0][0];
        lred[(w * 2 + 1) * 16 + col] = lacc[1][0];
    }
    __syncthreads();
    const int ri = tid >> 4;
    const int db = (tid & 15) << 2;
    float lf = 0.f, lb = 0.f;
    for (int w2 = 0; w2 < 4; ++w2) {
        lf += lred[(w2 * 2 + 0) * 16 + ri];
        lb += lred[(w2 * 2 + 1) * 16 + ri];
    }
    const float rf = 1.0f / lf;
    const float rb = 1.0f / lb;
    float acc[4];
    for (int kk = 0; kk < 4; ++kk) {
        float af = 0.f, ab = 0.f;
        for (int w2 = 0; w2 < 4; ++w2) {
            af += red[((w2 * 2 + 0) * 64 + db + kk) * 16 + ri];
            ab += red[((w2 * 2 + 1) * 64 + db + kk) * 16 + ri];
        }
        acc[kk] = af * rf + ab * rb;
    }
    float4 o = {acc[0], acc[1], acc[2], acc[3]};
    *(float4*)(O + (size_t)(b * LL + i0 + ri) * DD + db) = o;
}

extern "C" void kernel_launch(void* const* d_in, const int* in_sizes, int n_in,
                              void* d_out, int out_size, void* d_ws, size_t ws_size,
                              hipStream_t stream) {
    const float* q = (const float*)d_in[0];
    const float* k = (const float*)d_in[1];
    const float* v = (const float*)d_in[2];
    float* o = (float*)d_out;
    (void)in_sizes; (void)n_in; (void)out_size;

    // Kf + Vf: each [8][64] blocks x 4KB = 2MB -> 4MB total
    const size_t WS_NEED = (size_t)2 * BB * 64 * 1024 * 4 * sizeof(unsigned);
    if (ws_size >= WS_NEED) {
        unsigned* Kf = (unsigned*)d_ws;
        unsigned* Vf = Kf + (size_t)BB * 64 * 1024;
        prepack_v2<<<dim3(512), dim3(256), 0, stream>>>(k, v, Kf, Vf);
        attn_v5<<<dim3(512), dim3(256), 0, stream>>>(q, Kf, Vf, o);
    } else {
        attn_fused_v1<<<dim3(BB * (LL / 16)), dim3(256), 0, stream>>>(q, k, v, o);
    }
}